// Round 1
// baseline (805.302 us; speedup 1.0000x reference)
//
#include <hip/hip_runtime.h>
#include <cstdint>
#include <cstddef>

#define B_    16
#define P_    10
#define S_    128
#define D_    512
#define H_    8
#define DH_   64
#define DFF_  2048
#define VOC_  32000
#define NROW  160   // B*P
#define SIGMA 0.05f
#define LN_EPS 1e-6f

// JAX threefry mode: 1 = partitionable (default since jax 0.4.36), 0 = original
#define JAX_PARTITIONABLE 1

// ---------------- Threefry2x32 (bit-exact vs JAX) ----------------
struct U2 { uint32_t x, y; };

__host__ __device__ __forceinline__ U2 tf2x32(uint32_t k0, uint32_t k1,
                                              uint32_t x0, uint32_t x1) {
  uint32_t ks[3] = {k0, k1, k0 ^ k1 ^ 0x1BD11BDAu};
  x0 += ks[0]; x1 += ks[1];
  const int R0[4] = {13, 15, 26, 6};
  const int R1[4] = {17, 29, 16, 24};
#pragma unroll
  for (int i = 0; i < 5; ++i) {
    const int* r = (i & 1) ? R1 : R0;
#pragma unroll
    for (int j = 0; j < 4; ++j) {
      x0 += x1;
      x1 = (x1 << r[j]) | (x1 >> (32 - r[j]));
      x1 ^= x0;
    }
    x0 += ks[(i + 1) % 3];
    x1 += ks[(i + 2) % 3] + (uint32_t)(i + 1);
  }
  return {x0, x1};
}

__device__ __forceinline__ uint32_t jax_bits32(uint32_t k0, uint32_t k1, uint32_t j) {
#if JAX_PARTITIONABLE
  U2 o = tf2x32(k0, k1, 0u, j);      // counts = 64-bit iota, hi=0, lo=j
  return o.x ^ o.y;                   // 32-bit fold
#else
  // original: requires total size; not used this round
  return 0u;
#endif
}

// XLA ErfInv32 (Giles) polynomial — matches lax.erf_inv f32
__device__ __forceinline__ float erfinv32(float x) {
  float w = -log1pf(-x * x);
  float p;
  if (w < 5.0f) {
    w = w - 2.5f;
    p = 2.81022636e-08f;
    p = fmaf(p, w, 3.43273939e-07f);
    p = fmaf(p, w, -3.5233877e-06f);
    p = fmaf(p, w, -4.39150654e-06f);
    p = fmaf(p, w, 0.00021858087f);
    p = fmaf(p, w, -0.00125372503f);
    p = fmaf(p, w, -0.00417768164f);
    p = fmaf(p, w, 0.246640727f);
    p = fmaf(p, w, 1.50140941f);
  } else {
    w = sqrtf(w) - 3.0f;
    p = -0.000200214257f;
    p = fmaf(p, w, 0.000100950558f);
    p = fmaf(p, w, 0.00134934322f);
    p = fmaf(p, w, -0.00367342844f);
    p = fmaf(p, w, 0.00573950773f);
    p = fmaf(p, w, -0.0076224613f);
    p = fmaf(p, w, 0.00943887047f);
    p = fmaf(p, w, 1.00167406f);
    p = fmaf(p, w, 2.83297682f);
  }
  return p * x;
}

__device__ __forceinline__ float jax_normal(uint32_t k0, uint32_t k1, uint32_t j) {
  uint32_t b = jax_bits32(k0, k1, j);
  float u01 = __uint_as_float((b >> 9) | 0x3F800000u) - 1.0f;   // [0,1)
  const float lo = -0.99999994f;                                 // nextafter(-1,0)
  float u = fmaxf(lo, fmaf(u01, 2.0f, lo));                      // (hi-lo)==2.0f in f32
  return 1.41421356f * erfinv32(u);
}

__device__ __forceinline__ float jax_gumbel(uint32_t k0, uint32_t k1, uint32_t j) {
  uint32_t b = jax_bits32(k0, k1, j);
  float u01 = __uint_as_float((b >> 9) | 0x3F800000u) - 1.0f;
  const float tiny = 1.17549435e-38f;
  float u = fmaxf(tiny, u01 + tiny);
  return -logf(-logf(u));
}

// ---------------- Kernels ----------------

// Gather K,V by particle index I along axis 1
__global__ __launch_bounds__(256) void k_gather(const float* __restrict__ K,
                                                const float* __restrict__ V,
                                                const int* __restrict__ I,
                                                float* __restrict__ oK,
                                                float* __restrict__ oV) {
  size_t idx = (size_t)blockIdx.x * 256 + threadIdx.x;        // float4 index
  const size_t total = (size_t)NROW * S_ * (D_ / 4);
  if (idx >= total) return;
  int d4 = (int)(idx % (D_ / 4));
  size_t row = idx / (D_ / 4);                                 // bp*S + s
  int s = (int)(row % S_);
  int bp = (int)(row / S_);
  int b = bp / P_;
  int iv = I[row];
  size_t src = ((size_t)(b * P_ + iv) * S_ + s) * (D_ / 4) + d4;
  ((float4*)oK)[idx] = ((const float4*)K)[src];
  ((float4*)oV)[idx] = ((const float4*)V)[src];
}

// q,k,v = r@W + b (+ noise); scatter noisy k,v into K,V at slice t
__global__ __launch_bounds__(256) void k_qkv(const float* __restrict__ r,
    const float* __restrict__ Wq, const float* __restrict__ bq,
    const float* __restrict__ Wk, const float* __restrict__ bk,
    const float* __restrict__ Wv, const float* __restrict__ bv,
    const int* __restrict__ tptr, float* __restrict__ wsq,
    float* __restrict__ oK, float* __restrict__ oV,
    uint32_t k1a, uint32_t k1b, uint32_t k2a, uint32_t k2b,
    uint32_t k3a, uint32_t k3b) {
  __shared__ float s_r[D_];
  int bp = blockIdx.x, tid = threadIdx.x;
  s_r[tid] = r[bp * D_ + tid];
  s_r[tid + 256] = r[bp * D_ + tid + 256];
  __syncthreads();
  int ts = min(max(*tptr, 0), S_ - 1);
#pragma unroll
  for (int half = 0; half < 2; ++half) {
    int dout = tid + half * 256;
    float aq = bq[dout], ak = bk[dout], av = bv[dout];
    for (int d = 0; d < D_; ++d) {
      float rv = s_r[d];
      aq = fmaf(rv, Wq[d * D_ + dout], aq);
      ak = fmaf(rv, Wk[d * D_ + dout], ak);
      av = fmaf(rv, Wv[d * D_ + dout], av);
    }
    uint32_t j = (uint32_t)(bp * D_ + dout);
    wsq[j] = aq + SIGMA * jax_normal(k1a, k1b, j);
    oK[((size_t)bp * S_ + ts) * D_ + dout] = ak + SIGMA * jax_normal(k2a, k2b, j);
    oV[((size_t)bp * S_ + ts) * D_ + dout] = av + SIGMA * jax_normal(k3a, k3b, j);
  }
}

// attention: one block per (bp, h); 128 threads (one per s)
__global__ __launch_bounds__(128) void k_attn(const float* __restrict__ wsq,
    const float* __restrict__ oK, const float* __restrict__ oV,
    float* __restrict__ wsctx, float* __restrict__ wsattn) {
  __shared__ float s_q[DH_];
  __shared__ float s_attn[S_];
  __shared__ float red[S_];
  int bp = blockIdx.x >> 3, h = blockIdx.x & 7, tid = threadIdx.x;
  if (tid < DH_) s_q[tid] = wsq[bp * D_ + h * DH_ + tid];
  __syncthreads();
  const float4* krow = (const float4*)(oK + ((size_t)bp * S_ + tid) * D_ + h * DH_);
  const float4* q4 = (const float4*)s_q;
  float sc = 0.f;
#pragma unroll
  for (int d = 0; d < DH_ / 4; ++d) {
    float4 kv = krow[d], qv = q4[d];
    sc += qv.x * kv.x + qv.y * kv.y + qv.z * kv.z + qv.w * kv.w;
  }
  sc *= 0.125f;  // 1/sqrt(64)
  red[tid] = sc; __syncthreads();
  for (int s = 64; s > 0; s >>= 1) {
    if (tid < s) red[tid] = fmaxf(red[tid], red[tid + s]);
    __syncthreads();
  }
  float m = red[0]; __syncthreads();
  float e = expf(sc - m);
  red[tid] = e; __syncthreads();
  for (int s = 64; s > 0; s >>= 1) {
    if (tid < s) red[tid] += red[tid + s];
    __syncthreads();
  }
  float a = e / red[0];
  s_attn[tid] = a;
  wsattn[(size_t)blockIdx.x * S_ + tid] = a;
  __syncthreads();
  if (tid < DH_) {
    const float* vb = oV + (size_t)bp * S_ * D_ + h * DH_ + tid;
    float acc = 0.f;
    for (int s = 0; s < S_; ++s) acc = fmaf(s_attn[s], vb[(size_t)s * D_], acc);
    wsctx[bp * D_ + h * DH_ + tid] = acc;
  }
}

// attn_weights = mean over heads
__global__ __launch_bounds__(256) void k_aw(const float* __restrict__ wsattn,
                                            float* __restrict__ oaw) {
  int idx = blockIdx.x * 256 + threadIdx.x;   // 20480
  if (idx >= NROW * S_) return;
  int bp = idx / S_, s = idx % S_;
  float acc = 0.f;
#pragma unroll
  for (int h = 0; h < H_; ++h) acc += wsattn[(size_t)(bp * H_ + h) * S_ + s];
  oaw[idx] = acc * 0.125f;
}

// z = ctx@Wo + bo + eps;  out1 = LN(z + r)
__global__ __launch_bounds__(256) void k_zln(const float* __restrict__ wsctx,
    const float* __restrict__ Wo, const float* __restrict__ bo,
    const float* __restrict__ r, const float* __restrict__ g1,
    const float* __restrict__ be1, float* __restrict__ oeps,
    float* __restrict__ wsz, float* __restrict__ wsout1,
    uint32_t k4a, uint32_t k4b) {
  __shared__ float s_c[D_];
  __shared__ float s_x[D_];
  __shared__ float red[256];
  int bp = blockIdx.x, tid = threadIdx.x;
  s_c[tid] = wsctx[bp * D_ + tid];
  s_c[tid + 256] = wsctx[bp * D_ + tid + 256];
  __syncthreads();
#pragma unroll
  for (int half = 0; half < 2; ++half) {
    int dout = tid + half * 256;
    float acc = bo[dout];
    for (int d = 0; d < D_; ++d) acc = fmaf(s_c[d], Wo[d * D_ + dout], acc);
    uint32_t j = (uint32_t)(bp * D_ + dout);
    float eps = SIGMA * jax_normal(k4a, k4b, j);
    oeps[j] = eps;
    float z = acc + eps;
    wsz[j] = z;
    s_x[dout] = z + r[j];
  }
  __syncthreads();
  red[tid] = s_x[tid] + s_x[tid + 256]; __syncthreads();
  for (int s = 128; s > 0; s >>= 1) { if (tid < s) red[tid] += red[tid + s]; __syncthreads(); }
  float mu = red[0] / (float)D_; __syncthreads();
  float d0 = s_x[tid] - mu, d1 = s_x[tid + 256] - mu;
  red[tid] = d0 * d0 + d1 * d1; __syncthreads();
  for (int s = 128; s > 0; s >>= 1) { if (tid < s) red[tid] += red[tid + s]; __syncthreads(); }
  float inv = 1.0f / sqrtf(red[0] / (float)D_ + LN_EPS);
#pragma unroll
  for (int half = 0; half < 2; ++half) {
    int dout = tid + half * 256;
    wsout1[bp * D_ + dout] = g1[dout] * (s_x[dout] - mu) * inv + be1[dout];
  }
}

// ffn1 = relu(out1@W1 + b1)
__global__ __launch_bounds__(256) void k_ffn1(const float* __restrict__ wsout1,
    const float* __restrict__ W1, const float* __restrict__ b1,
    float* __restrict__ wsffn) {
  __shared__ float s_a[D_];
  int bp = blockIdx.x, tid = threadIdx.x;
  s_a[tid] = wsout1[bp * D_ + tid];
  s_a[tid + 256] = wsout1[bp * D_ + tid + 256];
  __syncthreads();
  float acc[8];
#pragma unroll
  for (int k = 0; k < 8; ++k) acc[k] = b1[tid + k * 256];
  for (int d = 0; d < D_; ++d) {
    float av = s_a[d];
    const float* wrow = W1 + (size_t)d * DFF_ + tid;
#pragma unroll
    for (int k = 0; k < 8; ++k) acc[k] = fmaf(av, wrow[k * 256], acc[k]);
  }
#pragma unroll
  for (int k = 0; k < 8; ++k)
    wsffn[(size_t)bp * DFF_ + tid + k * 256] = fmaxf(acc[k], 0.f);
}

// out3 = LN(ffn1@W2 + b2 + out1)
__global__ __launch_bounds__(256) void k_ffn2(const float* __restrict__ wsffn,
    const float* __restrict__ W2, const float* __restrict__ b2,
    const float* __restrict__ wsout1, const float* __restrict__ g3,
    const float* __restrict__ be3, float* __restrict__ oout3) {
  __shared__ float s_f[DFF_];
  __shared__ float s_x[D_];
  __shared__ float red[256];
  int bp = blockIdx.x, tid = threadIdx.x;
#pragma unroll
  for (int k = 0; k < 8; ++k) s_f[tid + k * 256] = wsffn[(size_t)bp * DFF_ + tid + k * 256];
  __syncthreads();
  float a0 = b2[tid], a1 = b2[tid + 256];
  for (int d = 0; d < DFF_; ++d) {
    float fv = s_f[d];
    a0 = fmaf(fv, W2[(size_t)d * D_ + tid], a0);
    a1 = fmaf(fv, W2[(size_t)d * D_ + tid + 256], a1);
  }
  s_x[tid] = a0 + wsout1[bp * D_ + tid];
  s_x[tid + 256] = a1 + wsout1[bp * D_ + tid + 256];
  __syncthreads();
  red[tid] = s_x[tid] + s_x[tid + 256]; __syncthreads();
  for (int s = 128; s > 0; s >>= 1) { if (tid < s) red[tid] += red[tid + s]; __syncthreads(); }
  float mu = red[0] / (float)D_; __syncthreads();
  float d0 = s_x[tid] - mu, d1 = s_x[tid + 256] - mu;
  red[tid] = d0 * d0 + d1 * d1; __syncthreads();
  for (int s = 128; s > 0; s >>= 1) { if (tid < s) red[tid] += red[tid + s]; __syncthreads(); }
  float inv = 1.0f / sqrtf(red[0] / (float)D_ + LN_EPS);
#pragma unroll
  for (int half = 0; half < 2; ++half) {
    int dout = tid + half * 256;
    oout3[bp * D_ + dout] = g3[dout] * (s_x[dout] - mu) * inv + be3[dout];
  }
}

// predictions = out3 @ Wout + bout  (160 x 512 x 32000), 32-row tiles
__global__ __launch_bounds__(256) void k_preds(const float* __restrict__ oout3,
    const float* __restrict__ Wout, const float* __restrict__ bout,
    float* __restrict__ wspred) {
  __shared__ float s_A[32][D_];   // 64 KB
  int tid = threadIdx.x;
  int r0 = blockIdx.y * 32;
  const float4* src = (const float4*)(oout3 + (size_t)r0 * D_);
  float4* dst = (float4*)&s_A[0][0];
#pragma unroll
  for (int k = 0; k < (32 * D_ / 4) / 256; ++k) dst[tid + k * 256] = src[tid + k * 256];
  __syncthreads();
  int c = blockIdx.x * 256 + tid;
  float acc[32];
  float bb = bout[c];
#pragma unroll
  for (int rr = 0; rr < 32; ++rr) acc[rr] = bb;
  for (int d = 0; d < D_; d += 4) {
    float w0 = Wout[(size_t)d * VOC_ + c];
    float w1 = Wout[(size_t)(d + 1) * VOC_ + c];
    float w2 = Wout[(size_t)(d + 2) * VOC_ + c];
    float w3 = Wout[(size_t)(d + 3) * VOC_ + c];
#pragma unroll
    for (int rr = 0; rr < 32; ++rr) {
      float4 a = *(const float4*)&s_A[rr][d];
      acc[rr] = fmaf(a.w, w3, fmaf(a.z, w2, fmaf(a.y, w1, fmaf(a.x, w0, acc[rr]))));
    }
  }
#pragma unroll
  for (int rr = 0; rr < 32; ++rr)
    wspred[(size_t)(r0 + rr) * VOC_ + c] = acc[rr];
}

// per-row softmax stats over VOC; w[b,p] = probs at x[b]
__global__ __launch_bounds__(256) void k_stats(const float* __restrict__ wspred,
    const int* __restrict__ x, float* __restrict__ ow) {
  __shared__ float red[256];
  int bp = blockIdx.x, tid = threadIdx.x;
  const float* row = wspred + (size_t)bp * VOC_;
  float m = -INFINITY;
  for (int c = tid; c < VOC_; c += 256) m = fmaxf(m, row[c]);
  red[tid] = m; __syncthreads();
  for (int s = 128; s > 0; s >>= 1) { if (tid < s) red[tid] = fmaxf(red[tid], red[tid + s]); __syncthreads(); }
  m = red[0]; __syncthreads();
  float sum = 0.f;
  for (int c = tid; c < VOC_; c += 256) sum += expf(row[c] - m);
  red[tid] = sum; __syncthreads();
  for (int s = 128; s > 0; s >>= 1) { if (tid < s) red[tid] += red[tid + s]; __syncthreads(); }
  if (tid == 0) {
    int b = bp / P_;
    ow[bp] = expf(row[x[b]] - m) / red[0];
  }
}

// i_t via gumbel-argmax; argmax_w per batch
__global__ __launch_bounds__(256) void k_it(const float* __restrict__ ow,
    int* __restrict__ wsit, int* __restrict__ wsamw,
    uint32_t k5a, uint32_t k5b) {
  int tid = threadIdx.x;
  if (tid < NROW) {
    int b = tid / P_;
    float best = -INFINITY; int bi = 0;
#pragma unroll
    for (int i = 0; i < P_; ++i) {
      float g = jax_gumbel(k5a, k5b, (uint32_t)(tid * P_ + i));
      float v = g + ow[b * P_ + i];
      if (v > best) { best = v; bi = i; }
    }
    wsit[tid] = bi;
  }
  if (tid < B_) {
    float best = -INFINITY; int bi = 0;
#pragma unroll
    for (int p = 0; p < P_; ++p) {
      float v = ow[tid * P_ + p];
      if (v > best) { best = v; bi = p; }
    }
    wsamw[tid] = bi;
  }
}

// average_prediction and max_prediction
__global__ __launch_bounds__(256) void k_avgmax(const float* __restrict__ wspred,
    const float* __restrict__ ow, const int* __restrict__ wsamw,
    float* __restrict__ oavg, float* __restrict__ omax) {
  int idx = blockIdx.x * 256 + threadIdx.x;   // 512000
  if (idx >= B_ * VOC_) return;
  int b = idx / VOC_, c = idx % VOC_;
  float acc = 0.f;
#pragma unroll
  for (int p = 0; p < P_; ++p)
    acc = fmaf(wspred[(size_t)(b * P_ + p) * VOC_ + c], ow[b * P_ + p], acc);
  oavg[idx] = acc;
  omax[idx] = wspred[(size_t)(b * P_ + wsamw[b]) * VOC_ + c];
}

// z selection by i_t + I_new
__global__ __launch_bounds__(256) void k_zsel(const float* __restrict__ wsz,
    const int* __restrict__ wsit, const int* __restrict__ I,
    const int* __restrict__ tptr, float* __restrict__ oz, float* __restrict__ oI) {
  int idx = blockIdx.x * 256 + threadIdx.x;
  if (idx < NROW * D_) {
    int bp = idx / D_, d = idx % D_;
    int b = bp / P_;
    oz[idx] = wsz[(size_t)(b * P_ + wsit[bp]) * D_ + d];
  }
  if (idx < NROW * S_) {
    int bp = idx / S_, s = idx % S_;
    int ts = min(max(*tptr, 0), S_ - 1);
    oI[idx] = (s == ts) ? (float)wsit[bp] : (float)I[idx];
  }
}

// ---------------- Host launch ----------------
static void derive_keys(uint32_t keys[5][2]) {
#if JAX_PARTITIONABLE
  for (int i = 0; i < 5; ++i) {
    U2 o = tf2x32(0u, 42u, 0u, (uint32_t)i);   // foldlike split
    keys[i][0] = o.x; keys[i][1] = o.y;
  }
#else
  uint32_t ox[5], oy[5];
  for (int i = 0; i < 5; ++i) {
    U2 o = tf2x32(0u, 42u, (uint32_t)i, (uint32_t)(5 + i));
    ox[i] = o.x; oy[i] = o.y;
  }
  uint32_t flat[10] = {ox[0], ox[1], ox[2], ox[3], ox[4], oy[0], oy[1], oy[2], oy[3], oy[4]};
  for (int i = 0; i < 5; ++i) { keys[i][0] = flat[2 * i]; keys[i][1] = flat[2 * i + 1]; }
#endif
}

extern "C" void kernel_launch(void* const* d_in, const int* in_sizes, int n_in,
                              void* d_out, int out_size, void* d_ws, size_t ws_size,
                              hipStream_t stream) {
  const float* r   = (const float*)d_in[0];
  const int*   x   = (const int*)d_in[1];
  const float* K   = (const float*)d_in[2];
  const float* V   = (const float*)d_in[3];
  const int*   I   = (const int*)d_in[5];
  const int*   tp  = (const int*)d_in[6];
  const float* Wq  = (const float*)d_in[7];
  const float* bq  = (const float*)d_in[8];
  const float* Wk  = (const float*)d_in[9];
  const float* bk  = (const float*)d_in[10];
  const float* Wv  = (const float*)d_in[11];
  const float* bv  = (const float*)d_in[12];
  const float* Wo  = (const float*)d_in[13];
  const float* bo  = (const float*)d_in[14];
  const float* W1  = (const float*)d_in[15];
  const float* b1  = (const float*)d_in[16];
  const float* W2  = (const float*)d_in[17];
  const float* b2  = (const float*)d_in[18];
  const float* g1  = (const float*)d_in[19];
  const float* be1 = (const float*)d_in[20];
  const float* g3  = (const float*)d_in[21];
  const float* be3 = (const float*)d_in[22];
  const float* Wout = (const float*)d_in[23];
  const float* bout = (const float*)d_in[24];

  float* out = (float*)d_out;
  // output offsets (return order)
  const size_t O_OUT3 = 0;
  const size_t O_Z    = 81920;
  const size_t O_AVG  = 163840;
  const size_t O_MAX  = 675840;
  const size_t O_EPS  = 1187840;
  const size_t O_AW   = 1269760;
  const size_t O_K    = 1290240;
  const size_t O_V    = 11776000;
  const size_t O_W    = 22261760;
  const size_t O_I    = 22261920;

  float* ws = (float*)d_ws;
  const size_t W_Q    = 0;        // 81920
  const size_t W_CTX  = 81920;    // 81920
  const size_t W_Z    = 163840;   // 81920
  const size_t W_OUT1 = 245760;   // 81920
  const size_t W_ATT  = 327680;   // 163840
  const size_t W_FFN  = 491520;   // 327680
  const size_t W_PRED = 819200;   // 5120000
  const size_t W_IT   = 5939200;  // 160 ints
  const size_t W_AMW  = 5939360;  // 16 ints

  uint32_t kk[5][2];
  derive_keys(kk);

  float* oK = out + O_K;
  float* oV = out + O_V;

  k_gather<<<10240, 256, 0, stream>>>(K, V, I, oK, oV);
  k_qkv<<<NROW, 256, 0, stream>>>(r, Wq, bq, Wk, bk, Wv, bv, tp,
                                  ws + W_Q, oK, oV,
                                  kk[0][0], kk[0][1], kk[1][0], kk[1][1],
                                  kk[2][0], kk[2][1]);
  k_attn<<<NROW * H_, 128, 0, stream>>>(ws + W_Q, oK, oV, ws + W_CTX, ws + W_ATT);
  k_aw<<<(NROW * S_ + 255) / 256, 256, 0, stream>>>(ws + W_ATT, out + O_AW);
  k_zln<<<NROW, 256, 0, stream>>>(ws + W_CTX, Wo, bo, r, g1, be1,
                                  out + O_EPS, ws + W_Z, ws + W_OUT1,
                                  kk[3][0], kk[3][1]);
  k_ffn1<<<NROW, 256, 0, stream>>>(ws + W_OUT1, W1, b1, ws + W_FFN);
  k_ffn2<<<NROW, 256, 0, stream>>>(ws + W_FFN, W2, b2, ws + W_OUT1, g3, be3,
                                   out + O_OUT3);
  k_preds<<<dim3(VOC_ / 256, NROW / 32), 256, 0, stream>>>(out + O_OUT3, Wout, bout,
                                                           ws + W_PRED);
  k_stats<<<NROW, 256, 0, stream>>>(ws + W_PRED, x, out + O_W);
  k_it<<<1, 256, 0, stream>>>(out + O_W, (int*)(ws + W_IT), (int*)(ws + W_AMW),
                              kk[4][0], kk[4][1]);
  k_avgmax<<<(B_ * VOC_ + 255) / 256, 256, 0, stream>>>(ws + W_PRED, out + O_W,
                                                        (const int*)(ws + W_AMW),
                                                        out + O_AVG, out + O_MAX);
  k_zsel<<<(NROW * D_ + 255) / 256, 256, 0, stream>>>(ws + W_Z, (const int*)(ws + W_IT),
                                                      I, tp, out + O_Z, out + O_I);
}